// Round 8
// baseline (244.189 us; speedup 1.0000x reference)
//
#include <hip/hip_runtime.h>
#include <stdint.h>

// B=2, H=16, S=2048, D=64. fp32 in, fp32 out. mask int32 [B,1,S,S].
// scores = QK^T/8, masked_fill(mask==0, -32768), softmax, @V.
// Fixed-max softmax in exp2 domain: p = exp2(s*log2e/8); masked -> exact 0.
//
// ROUND 17 == ROUND 16 resubmitted (container infra failure, no data; same
// as r11->r12 flake). Edits vs r15 (131us, 1.93e7 conflicts):
//  1. V^T staging role swap (vkq=tid&15, vdq=tid>>4). r15's roles put 16
//     quarter-wave lanes on 2 bank-groups (8-way conflict, 1.93e7 cycles =
//     24% of time). New roles: per write, a quarter-wave spans all 16 8B
//     slots of ONE row -> 32 banks each once = conflict-free.
//  2. SCL2 folded into Q fragments (scaled once in prologue) -> p =
//     exp2(sacc) directly; saves 16 v_mul/thread/tile.
//  3. s_setprio(1) around MFMA clusters (T5; co-resident blocks at
//     different phases -> scheduler favors MFMA waves).
// Structure (r15, verified): 32x32x16 MFMA, P in-register via
// v_cvt_pk_bf16_f32 + v_permlane32_swap_b32; K/V^T LDS 128B rows XOR
// swizzle byte^=((row&7)<<4); double-buffered; one lgkm-only barrier per
// 64-key tile; reg prefetch t+2, mask prefetch t+1 span barriers.

#define SS 2048
#define DD 64
#define KT 64
#define NT 32
#define QB 64

#define KS0 0
#define VT0 8192
#define KS1 16384
#define VT1 24576
#define SMEM_SZ 32768

#define SCL2 0.18033688011112042f  // log2(e)/8

typedef __attribute__((ext_vector_type(8))) short bf16x8;
typedef __attribute__((ext_vector_type(16))) float f32x16;

// pack two f32 -> two bf16 (RNE): low16 = bf16(f0), high16 = bf16(f1)
static __device__ __forceinline__ unsigned pk2(float f0, float f1) {
  unsigned r;
  asm("v_cvt_pk_bf16_f32 %0, %1, %2" : "=v"(r) : "v"(f0), "v"(f1));
  return r;
}

// v_permlane32_swap_b32 a, b:
//   a' = {a[0:31], b[0:31]}, b' = {a[32:63], b[32:63]}
#define LSWAP(A, B) asm("v_permlane32_swap_b32 %0, %1" : "+v"(A), "+v"(B))

// barrier with LDS visibility only: lgkmcnt(0) + s_barrier. vmcnt untouched so
// register prefetches issued this iteration stay in flight across it.
#define BAR() do {                              \
  asm volatile("" ::: "memory");                \
  __builtin_amdgcn_s_waitcnt(0xC07F);           \
  __builtin_amdgcn_s_barrier();                 \
  asm volatile("" ::: "memory");                \
} while (0)

#define MFMA32(A, B, C) __builtin_amdgcn_mfma_f32_32x32x16_bf16((A), (B), (C), 0, 0, 0)

__global__ __launch_bounds__(256, 2)
void attn_mfma(const float* __restrict__ Q, const float* __restrict__ K,
               const float* __restrict__ V, const int* __restrict__ mask,
               float* __restrict__ out) {
  __shared__ alignas(16) uint8_t smem[SMEM_SZ];

  const int tid = threadIdx.x;
  const int wv = tid >> 6;
  const int l = tid & 63;
  const int l31 = l & 31;   // MFMA n-dim (q) / m-dim (key,d) lane index
  const int h = l >> 5;     // lane half: k-dim slice 8h+j
  const int x7 = l & 7;     // row-XOR (row&7 == l&7 for rows base+l31)

  const int qg = wv & 1;    // q-group within block (32 q each)
  const int kg = wv >> 1;   // key-group within tile (32 keys each)

  const int bid = blockIdx.x;  // 1024 = 32 (b,h) x 32 q-blocks
  const int qblk = bid & 31;
  const int bh = bid >> 5;
  const int b = bh >> 4;
  const size_t base = (size_t)bh * SS * DD;
  const int qrow = qblk * QB + 32 * qg + l31;  // this lane's query row

  // K staging: row kr (key), 16-col chunk kq. 2x b128 per thread.
  const int kr = tid >> 2;
  const int kq = tid & 3;
  // V^T staging roles (r16): key-quad vkq = tid&15, d-quad vdq = tid>>4.
  // Per write i: quarter-wave lanes have vkq = 0..15 (all 16 8B slots of one
  // row), row&7 constant -> 32 banks each exactly once = conflict-free.
  const int vkq = tid & 15;
  const int vdq = tid >> 4;

  // ---- Q fragments (one-time), PRE-SCALED by SCL2:
  // B[n=q=l31][k=8h+j] per d-slice s: d=16s+8h+j
  bf16x8 qf0, qf1, qf2, qf3;
  {
    const float* qp = Q + base + (size_t)qrow * DD + 8 * h;
    uint4 pk;
    float4 qa, qb;
    qa = *(const float4*)(qp);      qb = *(const float4*)(qp + 4);
    pk.x = pk2(qa.x * SCL2, qa.y * SCL2); pk.y = pk2(qa.z * SCL2, qa.w * SCL2);
    pk.z = pk2(qb.x * SCL2, qb.y * SCL2); pk.w = pk2(qb.z * SCL2, qb.w * SCL2);
    qf0 = __builtin_bit_cast(bf16x8, pk);
    qa = *(const float4*)(qp + 16); qb = *(const float4*)(qp + 20);
    pk.x = pk2(qa.x * SCL2, qa.y * SCL2); pk.y = pk2(qa.z * SCL2, qa.w * SCL2);
    pk.z = pk2(qb.x * SCL2, qb.y * SCL2); pk.w = pk2(qb.z * SCL2, qb.w * SCL2);
    qf1 = __builtin_bit_cast(bf16x8, pk);
    qa = *(const float4*)(qp + 32); qb = *(const float4*)(qp + 36);
    pk.x = pk2(qa.x * SCL2, qa.y * SCL2); pk.y = pk2(qa.z * SCL2, qa.w * SCL2);
    pk.z = pk2(qb.x * SCL2, qb.y * SCL2); pk.w = pk2(qb.z * SCL2, qb.w * SCL2);
    qf2 = __builtin_bit_cast(bf16x8, pk);
    qa = *(const float4*)(qp + 48); qb = *(const float4*)(qp + 52);
    pk.x = pk2(qa.x * SCL2, qa.y * SCL2); pk.y = pk2(qa.z * SCL2, qa.w * SCL2);
    pk.z = pk2(qb.x * SCL2, qb.y * SCL2); pk.w = pk2(qb.z * SCL2, qb.w * SCL2);
    qf3 = __builtin_bit_cast(bf16x8, pk);
  }

  // O^T accumulators: oacc[dg] reg x -> O[q=qrow][d = 32dg + (x&3)+8(x>>2)+4h]
  f32x16 oacc0 = {0.f,0.f,0.f,0.f,0.f,0.f,0.f,0.f,0.f,0.f,0.f,0.f,0.f,0.f,0.f,0.f};
  f32x16 oacc1 = {0.f,0.f,0.f,0.f,0.f,0.f,0.f,0.f,0.f,0.f,0.f,0.f,0.f,0.f,0.f,0.f};
  float lrun = 0.f;  // own-16-keys partial

  float4 kL0, kL1, kL2, kL3, vL0, vL1, vL2, vL3;

#define LOADKV(T) do {                                                    \
    const float* kp_ = K + base + (size_t)((T)*KT + kr) * DD + kq * 16;   \
    kL0 = *(const float4*)(kp_);                                          \
    kL1 = *(const float4*)(kp_ + 4);                                      \
    kL2 = *(const float4*)(kp_ + 8);                                      \
    kL3 = *(const float4*)(kp_ + 12);                                     \
    const float* vp_ = V + base + (size_t)((T)*KT + 4 * vkq) * DD + 4 * vdq;\
    vL0 = *(const float4*)(vp_);                                          \
    vL1 = *(const float4*)(vp_ + DD);                                     \
    vL2 = *(const float4*)(vp_ + 2 * DD);                                 \
    vL3 = *(const float4*)(vp_ + 3 * DD);                                 \
  } while (0)

  // K rows: 64 x 128B, logical chunk c stored at ((c ^ (row&7))<<4).
  // V^T rows: 64 x 128B (row=d), keys consecutive; 8B sub-slot 8*(vkq&1).
#define STAGE(KB, VB) do {                                                \
    uint4 c_;                                                             \
    c_.x = pk2(kL0.x, kL0.y); c_.y = pk2(kL0.z, kL0.w);                   \
    c_.z = pk2(kL1.x, kL1.y); c_.w = pk2(kL1.z, kL1.w);                   \
    *(uint4*)((KB) + kr * 128 + (((2 * kq) ^ (kr & 7)) << 4)) = c_;       \
    c_.x = pk2(kL2.x, kL2.y); c_.y = pk2(kL2.z, kL2.w);                   \
    c_.z = pk2(kL3.x, kL3.y); c_.w = pk2(kL3.z, kL3.w);                   \
    *(uint4*)((KB) + kr * 128 + (((2 * kq + 1) ^ (kr & 7)) << 4)) = c_;   \
    uint2 w_;                                                             \
    w_.x = pk2(vL0.x, vL1.x); w_.y = pk2(vL2.x, vL3.x);                   \
    *(uint2*)((VB) + (4*vdq+0) * 128 + ((((vkq >> 1) ^ ((4*vdq+0) & 7)) << 4)) + 8 * (vkq & 1)) = w_; \
    w_.x = pk2(vL0.y, vL1.y); w_.y = pk2(vL2.y, vL3.y);                   \
    *(uint2*)((VB) + (4*vdq+1) * 128 + ((((vkq >> 1) ^ ((4*vdq+1) & 7)) << 4)) + 8 * (vkq & 1)) = w_; \
    w_.x = pk2(vL0.z, vL1.z); w_.y = pk2(vL2.z, vL3.z);                   \
    *(uint2*)((VB) + (4*vdq+2) * 128 + ((((vkq >> 1) ^ ((4*vdq+2) & 7)) << 4)) + 8 * (vkq & 1)) = w_; \
    w_.x = pk2(vL0.w, vL1.w); w_.y = pk2(vL2.w, vL3.w);                   \
    *(uint2*)((VB) + (4*vdq+3) * 128 + ((((vkq >> 1) ^ ((4*vdq+3) & 7)) << 4)) + 8 * (vkq & 1)) = w_; \
  } while (0)

  // ---- prologue: tile 0 staged to buf0; tile 1 in regs; mask tile 0 in regs
  LOADKV(0);
  STAGE(smem + KS0, smem + VT0);
  LOADKV(1);

  // mask: lane needs keys 32kg + 4h + {0..3, 8..11, 16..19, 24..27} of its qrow
  const int* mbase = mask + (size_t)b * SS * SS + (size_t)qrow * SS + 32 * kg + 4 * h;
  int4 mi0 = *(const int4*)(mbase + 0);
  int4 mi1 = *(const int4*)(mbase + 8);
  int4 mi2 = *(const int4*)(mbase + 16);
  int4 mi3 = *(const int4*)(mbase + 24);

  BAR();

  for (int t = 0; t < NT; ++t) {
    const int db = t & 1;
    uint8_t* kbc = smem + (db ? KS1 : KS0);
    uint8_t* vbc = smem + (db ? VT1 : VT0);
    uint8_t* kbn = smem + (db ? KS0 : KS1);
    uint8_t* vbn = smem + (db ? VT0 : VT1);

    // ---- stage tile t+1 (regs from last iter) into the other buffer
    STAGE(kbn, vbn);

    // ---- prefetch tile t+2 K/V into regs (spans barrier; vmcnt never drained)
    const int tp2 = (t + 2 < NT) ? (t + 2) : (NT - 1);
    LOADKV(tp2);
    // ---- prefetch mask tile t+1
    const int tp1 = (t + 1 < NT) ? (t + 1) : (NT - 1);
    int4 mn0 = *(const int4*)(mbase + tp1 * KT + 0);
    int4 mn1 = *(const int4*)(mbase + tp1 * KT + 8);
    int4 mn2 = *(const int4*)(mbase + tp1 * KT + 16);
    int4 mn3 = *(const int4*)(mbase + tp1 * KT + 24);

    // ---- QK: S^T[key][q], 4 MFMAs over d-slices. A = K frag from LDS:
    // row = 32kg+l31, chunk = 2s+h (d = 16s+8h+j), swizzled by row&7 == x7.
    f32x16 sacc = {0.f,0.f,0.f,0.f,0.f,0.f,0.f,0.f,0.f,0.f,0.f,0.f,0.f,0.f,0.f,0.f};
    {
      const uint8_t* krow = kbc + (32 * kg + l31) * 128;
      bf16x8 kf0 = *(const bf16x8*)(krow + (((0 + h) ^ x7) << 4));
      bf16x8 kf1 = *(const bf16x8*)(krow + (((2 + h) ^ x7) << 4));
      bf16x8 kf2 = *(const bf16x8*)(krow + (((4 + h) ^ x7) << 4));
      bf16x8 kf3 = *(const bf16x8*)(krow + (((6 + h) ^ x7) << 4));
      __builtin_amdgcn_s_setprio(1);
      sacc = MFMA32(kf0, qf0, sacc);
      sacc = MFMA32(kf1, qf1, sacc);
      sacc = MFMA32(kf2, qf2, sacc);
      sacc = MFMA32(kf3, qf3, sacc);
      __builtin_amdgcn_s_setprio(0);
    }

    // ---- softmax: p = exp2(s) (SCL2 pre-folded into Q), masked -> 0.
    // reg x holds local key (x&3)+8*(x>>2)+4h; mask int4 m=(x>>2), comp (x&3).
    float p0  = (mi0.x != 0) ? __builtin_amdgcn_exp2f(sacc[0])  : 0.f;
    float p1  = (mi0.y != 0) ? __builtin_amdgcn_exp2f(sacc[1])  : 0.f;
    float p2  = (mi0.z != 0) ? __builtin_amdgcn_exp2f(sacc[2])  : 0.f;
    float p3  = (mi0.w != 0) ? __builtin_amdgcn_exp2f(sacc[3])  : 0.f;
    float p4  = (mi1.x != 0) ? __builtin_amdgcn_exp2f(sacc[4])  : 0.f;
    float p5  = (mi1.y != 0) ? __builtin_amdgcn_exp2f(sacc[5])  : 0.f;
    float p6  = (mi1.z != 0) ? __builtin_amdgcn_exp2f(sacc[6])  : 0.f;
    float p7  = (mi1.w != 0) ? __builtin_amdgcn_exp2f(sacc[7])  : 0.f;
    float p8  = (mi2.x != 0) ? __builtin_amdgcn_exp2f(sacc[8])  : 0.f;
    float p9  = (mi2.y != 0) ? __builtin_amdgcn_exp2f(sacc[9])  : 0.f;
    float p10 = (mi2.z != 0) ? __builtin_amdgcn_exp2f(sacc[10]) : 0.f;
    float p11 = (mi2.w != 0) ? __builtin_amdgcn_exp2f(sacc[11]) : 0.f;
    float p12 = (mi3.x != 0) ? __builtin_amdgcn_exp2f(sacc[12]) : 0.f;
    float p13 = (mi3.y != 0) ? __builtin_amdgcn_exp2f(sacc[13]) : 0.f;
    float p14 = (mi3.z != 0) ? __builtin_amdgcn_exp2f(sacc[14]) : 0.f;
    float p15 = (mi3.w != 0) ? __builtin_amdgcn_exp2f(sacc[15]) : 0.f;
    lrun += ((p0 + p1) + (p2 + p3)) + ((p4 + p5) + (p6 + p7)) +
            ((p8 + p9) + (p10 + p11)) + ((p12 + p13) + (p14 + p15));

    // ---- P -> PV B-operand, fully in-register.
    // pk[i] = bf16pair(p[2i], p[2i+1]) covers keys 8*(i>>1)+2*(i&1)+4h (+1).
    // B-frag[ks] word w holds keys 16ks+8h+2w,+1. w<2 sources the LOWER
    // half-wave's pk, w>=2 the UPPER's; LSWAP routes both halves correctly.
    unsigned k0 = pk2(p0, p1),   k1 = pk2(p2, p3),
             k2 = pk2(p4, p5),   k3 = pk2(p6, p7),
             k4 = pk2(p8, p9),   k5 = pk2(p10, p11),
             k6 = pk2(p12, p13), k7 = pk2(p14, p15);
    uint4 bw;
    LSWAP(k0, k2);  // k0 -> word0 (ks=0), k2 -> word2
    LSWAP(k1, k3);  // k1 -> word1, k3 -> word3
    bw.x = k0; bw.y = k1; bw.z = k2; bw.w = k3;
    bf16x8 pB0 = __builtin_bit_cast(bf16x8, bw);
    LSWAP(k4, k6);
    LSWAP(k5, k7);
    bw.x = k4; bw.y = k5; bw.z = k6; bw.w = k7;
    bf16x8 pB1 = __builtin_bit_cast(bf16x8, bw);

    // ---- PV: O^T[d][q] += V^T.P^T. A = V^T frag: row d = 32dg+l31,
    // chunk = 4kg+2ks+h (keys 32kg+16ks+8h+j), swizzle row&7 == x7.
    {
      const uint8_t* vrow0 = vbc + (l31) * 128;        // dg=0
      const uint8_t* vrow1 = vbc + (32 + l31) * 128;   // dg=1
      bf16x8 vf0 = *(const bf16x8*)(vrow0 + (((4 * kg + 0 + h) ^ x7) << 4));
      bf16x8 vf1 = *(const bf16x8*)(vrow0 + (((4 * kg + 2 + h) ^ x7) << 4));
      bf16x8 vf2 = *(const bf16x8*)(vrow1 + (((4 * kg + 0 + h) ^ x7) << 4));
      bf16x8 vf3 = *(const bf16x8*)(vrow1 + (((4 * kg + 2 + h) ^ x7) << 4));
      __builtin_amdgcn_s_setprio(1);
      oacc0 = MFMA32(vf0, pB0, oacc0);
      oacc0 = MFMA32(vf1, pB1, oacc0);
      oacc1 = MFMA32(vf2, pB0, oacc1);
      oacc1 = MFMA32(vf3, pB1, oacc1);
      __builtin_amdgcn_s_setprio(0);
    }

    mi0 = mn0; mi1 = mn1; mi2 = mn2; mi3 = mn3;

    // ---- single barrier: WAR on buf[cur] + visibility of buf[nxt] staging.
    BAR();
  }

  // ---- epilogue 1: combine lane-pair (l <-> l+32) denominators via shfl
  // (guaranteed semantics; LSWAP-with-identical-operands degenerates: r14).
  const float l32 = lrun + __shfl_xor(lrun, 32);

  // ---- epilogue 2: cross-wave (kg=0 <-> kg=1) reduction via dead K/V LDS.
  // Waves 0,2 share qg=0 rows; waves 1,3 share qg=1. kg=1 writes partials,
  // kg=0 combines + stores. Padded stride 68 floats (<=8-way, once/block).
  float* xs = (float*)smem;
  const int xbase = qg * 2176 + l31 * 68;  // [qg][q=l31][d], stride 68
  if (kg == 1) {
#pragma unroll
    for (int xq = 0; xq < 4; ++xq) {
      float4 o;
      o.x = oacc0[4*xq+0]; o.y = oacc0[4*xq+1]; o.z = oacc0[4*xq+2]; o.w = oacc0[4*xq+3];
      *(float4*)(xs + xbase + 8 * xq + 4 * h) = o;         // d = 8xq+4h..+3
      o.x = oacc1[4*xq+0]; o.y = oacc1[4*xq+1]; o.z = oacc1[4*xq+2]; o.w = oacc1[4*xq+3];
      *(float4*)(xs + xbase + 32 + 8 * xq + 4 * h) = o;    // d = 32+8xq+4h..+3
    }
    if (h == 0) xs[4352 + qg * 32 + l31] = l32;
  }
  BAR();
  if (kg == 0) {
    const float ltot = l32 + xs[4352 + qg * 32 + l31];
    const float inv = (ltot > 0.f) ? (1.f / ltot) : 0.f;
    float* orow = out + base + (size_t)qrow * DD;
#pragma unroll
    for (int xq = 0; xq < 4; ++xq) {
      float4 po = *(const float4*)(xs + xbase + 8 * xq + 4 * h);
      float4 o;
      o.x = (oacc0[4*xq+0] + po.x) * inv;
      o.y = (oacc0[4*xq+1] + po.y) * inv;
      o.z = (oacc0[4*xq+2] + po.z) * inv;
      o.w = (oacc0[4*xq+3] + po.w) * inv;
      *(float4*)(orow + 8 * xq + 4 * h) = o;
      po = *(const float4*)(xs + xbase + 32 + 8 * xq + 4 * h);
      o.x = (oacc1[4*xq+0] + po.x) * inv;
      o.y = (oacc1[4*xq+1] + po.y) * inv;
      o.z = (oacc1[4*xq+2] + po.z) * inv;
      o.w = (oacc1[4*xq+3] + po.w) * inv;
      *(float4*)(orow + 32 + 8 * xq + 4 * h) = o;
    }
  }
}

extern "C" void kernel_launch(void* const* d_in, const int* in_sizes, int n_in,
                              void* d_out, int out_size, void* d_ws, size_t ws_size,
                              hipStream_t stream) {
  (void)in_sizes; (void)n_in; (void)out_size; (void)d_ws; (void)ws_size;
  const float* Q = (const float*)d_in[0];
  const float* K = (const float*)d_in[1];
  const float* V = (const float*)d_in[2];
  const int* mask = (const int*)d_in[3];
  float* out = (float*)d_out;
  attn_mfma<<<1024, 256, 0, stream>>>(Q, K, V, mask, out);
}

// Round 9
// 210.227 us; speedup vs baseline: 1.1615x; 1.1615x over previous
//
#include <hip/hip_runtime.h>
#include <stdint.h>

// B=2, H=16, S=2048, D=64. fp32 in, fp32 out. mask int32 [B,1,S,S].
// scores = QK^T/8, masked_fill(mask==0, -32768), softmax, @V.
// Fixed-max softmax in exp2 domain: p = exp2(s*log2e/8); masked -> exact 0.
//
// ROUND 18 (from r15=131us/1.93e7-conf and r17=168us/4.2e6-conf):
//  r17 taught: V-write conflicts fixed but V global loads became 64-way
//  scattered (16B @ 1KB stride) -> +37us stall. Resolution: keep r15's
//  COALESCED V roles and fix conflicts in the swizzle function instead:
//    V^T swizzle: chunk ^= (row&7) ^ ((row>>3)&7)   [two-level XOR]
//  - writes (rows 4vc+i): row>>3=vc>>1 spans 0..7 -> 2 lanes/bank (free)
//  - reads (rows 32dg+l31): extra term constant per 8-row window -> same
//    <=2-way as the measured-clean r15 read path.
//  Also dropped: s_setprio (null-to-negative on barrier-locked lockstep).
//  Kept: SCL2 pre-folded into Q fragments.
// Structure (r15, verified): 32x32x16 MFMA, P in-register via
// v_cvt_pk_bf16_f32 + v_permlane32_swap_b32; K LDS swizzle chunk^=(row&7);
// double-buffered; one lgkm-only barrier per 64-key tile; reg prefetch
// t+2, mask prefetch t+1 span barriers (vmcnt never drained in loop).

#define SS 2048
#define DD 64
#define KT 64
#define NT 32
#define QB 64

#define KS0 0
#define VT0 8192
#define KS1 16384
#define VT1 24576
#define SMEM_SZ 32768

#define SCL2 0.18033688011112042f  // log2(e)/8

typedef __attribute__((ext_vector_type(8))) short bf16x8;
typedef __attribute__((ext_vector_type(16))) float f32x16;

// pack two f32 -> two bf16 (RNE): low16 = bf16(f0), high16 = bf16(f1)
static __device__ __forceinline__ unsigned pk2(float f0, float f1) {
  unsigned r;
  asm("v_cvt_pk_bf16_f32 %0, %1, %2" : "=v"(r) : "v"(f0), "v"(f1));
  return r;
}

// v_permlane32_swap_b32 a, b:
//   a' = {a[0:31], b[0:31]}, b' = {a[32:63], b[32:63]}
#define LSWAP(A, B) asm("v_permlane32_swap_b32 %0, %1" : "+v"(A), "+v"(B))

// barrier with LDS visibility only: lgkmcnt(0) + s_barrier. vmcnt untouched so
// register prefetches issued this iteration stay in flight across it.
#define BAR() do {                              \
  asm volatile("" ::: "memory");                \
  __builtin_amdgcn_s_waitcnt(0xC07F);           \
  __builtin_amdgcn_s_barrier();                 \
  asm volatile("" ::: "memory");                \
} while (0)

#define MFMA32(A, B, C) __builtin_amdgcn_mfma_f32_32x32x16_bf16((A), (B), (C), 0, 0, 0)

__global__ __launch_bounds__(256, 2)
void attn_mfma(const float* __restrict__ Q, const float* __restrict__ K,
               const float* __restrict__ V, const int* __restrict__ mask,
               float* __restrict__ out) {
  __shared__ alignas(16) uint8_t smem[SMEM_SZ];

  const int tid = threadIdx.x;
  const int wv = tid >> 6;
  const int l = tid & 63;
  const int l31 = l & 31;   // MFMA n-dim (q) / m-dim (key,d) lane index
  const int h = l >> 5;     // lane half: k-dim slice 8h+j
  const int x7 = l & 7;     // row&7 for K rows base+l31

  const int qg = wv & 1;    // q-group within block (32 q each)
  const int kg = wv >> 1;   // key-group within tile (32 keys each)

  const int bid = blockIdx.x;  // 1024 = 32 (b,h) x 32 q-blocks
  const int qblk = bid & 31;
  const int bh = bid >> 5;
  const int b = bh >> 4;
  const size_t base = (size_t)bh * SS * DD;
  const int qrow = qblk * QB + 32 * qg + l31;  // this lane's query row

  // K staging: row kr (key), 16-col chunk kq. 2x b128 per thread.
  const int kr = tid >> 2;
  const int kq = tid & 3;
  // V staging roles (r15, coalesced): key-quad va_ = tid>>4, d-quad vc = tid&15.
  // Global: quarter-wave reads 256B contiguous of one key row.
  const int va_ = tid >> 4;
  const int vc = tid & 15;
  // V^T write swizzle pieces: row_i = 4vc+i -> row&7 = 4(vc&1)+i, row>>3 = vc>>1.
  const int vc1 = 4 * (vc & 1);
  const int vch = vc >> 1;
  const int vsub = 8 * (va_ & 1);
  const int vcq = va_ >> 1;
  // V^T read swizzle: g(row=32dg+l31) = x7 ^ (l31>>3) ^ 4dg
  const int gvx = x7 ^ (l31 >> 3);

  // ---- Q fragments (one-time), PRE-SCALED by SCL2:
  // B[n=q=l31][k=8h+j] per d-slice s: d=16s+8h+j
  bf16x8 qf0, qf1, qf2, qf3;
  {
    const float* qp = Q + base + (size_t)qrow * DD + 8 * h;
    uint4 pk;
    float4 qa, qb;
    qa = *(const float4*)(qp);      qb = *(const float4*)(qp + 4);
    pk.x = pk2(qa.x * SCL2, qa.y * SCL2); pk.y = pk2(qa.z * SCL2, qa.w * SCL2);
    pk.z = pk2(qb.x * SCL2, qb.y * SCL2); pk.w = pk2(qb.z * SCL2, qb.w * SCL2);
    qf0 = __builtin_bit_cast(bf16x8, pk);
    qa = *(const float4*)(qp + 16); qb = *(const float4*)(qp + 20);
    pk.x = pk2(qa.x * SCL2, qa.y * SCL2); pk.y = pk2(qa.z * SCL2, qa.w * SCL2);
    pk.z = pk2(qb.x * SCL2, qb.y * SCL2); pk.w = pk2(qb.z * SCL2, qb.w * SCL2);
    qf1 = __builtin_bit_cast(bf16x8, pk);
    qa = *(const float4*)(qp + 32); qb = *(const float4*)(qp + 36);
    pk.x = pk2(qa.x * SCL2, qa.y * SCL2); pk.y = pk2(qa.z * SCL2, qa.w * SCL2);
    pk.z = pk2(qb.x * SCL2, qb.y * SCL2); pk.w = pk2(qb.z * SCL2, qb.w * SCL2);
    qf2 = __builtin_bit_cast(bf16x8, pk);
    qa = *(const float4*)(qp + 48); qb = *(const float4*)(qp + 52);
    pk.x = pk2(qa.x * SCL2, qa.y * SCL2); pk.y = pk2(qa.z * SCL2, qa.w * SCL2);
    pk.z = pk2(qb.x * SCL2, qb.y * SCL2); pk.w = pk2(qb.z * SCL2, qb.w * SCL2);
    qf3 = __builtin_bit_cast(bf16x8, pk);
  }

  // O^T accumulators: oacc[dg] reg x -> O[q=qrow][d = 32dg + (x&3)+8(x>>2)+4h]
  f32x16 oacc0 = {0.f,0.f,0.f,0.f,0.f,0.f,0.f,0.f,0.f,0.f,0.f,0.f,0.f,0.f,0.f,0.f};
  f32x16 oacc1 = {0.f,0.f,0.f,0.f,0.f,0.f,0.f,0.f,0.f,0.f,0.f,0.f,0.f,0.f,0.f,0.f};
  float lrun = 0.f;  // own-16-keys partial

  float4 kL0, kL1, kL2, kL3, vL0, vL1, vL2, vL3;

#define LOADKV(T) do {                                                    \
    const float* kp_ = K + base + (size_t)((T)*KT + kr) * DD + kq * 16;   \
    kL0 = *(const float4*)(kp_);                                          \
    kL1 = *(const float4*)(kp_ + 4);                                      \
    kL2 = *(const float4*)(kp_ + 8);                                      \
    kL3 = *(const float4*)(kp_ + 12);                                     \
    const float* vp_ = V + base + (size_t)((T)*KT + 4 * va_) * DD + 4 * vc;\
    vL0 = *(const float4*)(vp_);                                          \
    vL1 = *(const float4*)(vp_ + DD);                                     \
    vL2 = *(const float4*)(vp_ + 2 * DD);                                 \
    vL3 = *(const float4*)(vp_ + 3 * DD);                                 \
  } while (0)

  // K rows: 64 x 128B, logical chunk c stored at ((c ^ (row&7))<<4).
  // V^T rows: 64 x 128B (row=d), chunk c=key>>3 stored at
  // ((c ^ (row&7) ^ ((row>>3)&7))<<4); 8B sub-slot 8*(va_&1).
  // Write i: row=4vc+i, keys 4va_..+3: w_ = {pk2(vL0[i],vL1[i]), pk2(vL2[i],vL3[i])}.
#define STAGE(KB, VB) do {                                                \
    uint4 c_;                                                             \
    c_.x = pk2(kL0.x, kL0.y); c_.y = pk2(kL0.z, kL0.w);                   \
    c_.z = pk2(kL1.x, kL1.y); c_.w = pk2(kL1.z, kL1.w);                   \
    *(uint4*)((KB) + kr * 128 + (((2 * kq) ^ (kr & 7)) << 4)) = c_;       \
    c_.x = pk2(kL2.x, kL2.y); c_.y = pk2(kL2.z, kL2.w);                   \
    c_.z = pk2(kL3.x, kL3.y); c_.w = pk2(kL3.z, kL3.w);                   \
    *(uint4*)((KB) + kr * 128 + (((2 * kq + 1) ^ (kr & 7)) << 4)) = c_;   \
    uint2 w_;                                                             \
    w_.x = pk2(vL0.x, vL1.x); w_.y = pk2(vL2.x, vL3.x);                   \
    *(uint2*)((VB) + (4*vc+0) * 128 + (((vcq ^ (vc1 + 0) ^ vch) << 4)) + vsub) = w_; \
    w_.x = pk2(vL0.y, vL1.y); w_.y = pk2(vL2.y, vL3.y);                   \
    *(uint2*)((VB) + (4*vc+1) * 128 + (((vcq ^ (vc1 + 1) ^ vch) << 4)) + vsub) = w_; \
    w_.x = pk2(vL0.z, vL1.z); w_.y = pk2(vL2.z, vL3.z);                   \
    *(uint2*)((VB) + (4*vc+2) * 128 + (((vcq ^ (vc1 + 2) ^ vch) << 4)) + vsub) = w_; \
    w_.x = pk2(vL0.w, vL1.w); w_.y = pk2(vL2.w, vL3.w);                   \
    *(uint2*)((VB) + (4*vc+3) * 128 + (((vcq ^ (vc1 + 3) ^ vch) << 4)) + vsub) = w_; \
  } while (0)

  // ---- prologue: tile 0 staged to buf0; tile 1 in regs; mask tile 0 in regs
  LOADKV(0);
  STAGE(smem + KS0, smem + VT0);
  LOADKV(1);

  // mask: lane needs keys 32kg + 4h + {0..3, 8..11, 16..19, 24..27} of its qrow
  const int* mbase = mask + (size_t)b * SS * SS + (size_t)qrow * SS + 32 * kg + 4 * h;
  int4 mi0 = *(const int4*)(mbase + 0);
  int4 mi1 = *(const int4*)(mbase + 8);
  int4 mi2 = *(const int4*)(mbase + 16);
  int4 mi3 = *(const int4*)(mbase + 24);

  BAR();

  for (int t = 0; t < NT; ++t) {
    const int db = t & 1;
    uint8_t* kbc = smem + (db ? KS1 : KS0);
    uint8_t* vbc = smem + (db ? VT1 : VT0);
    uint8_t* kbn = smem + (db ? KS0 : KS1);
    uint8_t* vbn = smem + (db ? VT0 : VT1);

    // ---- stage tile t+1 (regs from last iter) into the other buffer
    STAGE(kbn, vbn);

    // ---- prefetch tile t+2 K/V into regs (spans barrier; vmcnt never drained)
    const int tp2 = (t + 2 < NT) ? (t + 2) : (NT - 1);
    LOADKV(tp2);
    // ---- prefetch mask tile t+1
    const int tp1 = (t + 1 < NT) ? (t + 1) : (NT - 1);
    int4 mn0 = *(const int4*)(mbase + tp1 * KT + 0);
    int4 mn1 = *(const int4*)(mbase + tp1 * KT + 8);
    int4 mn2 = *(const int4*)(mbase + tp1 * KT + 16);
    int4 mn3 = *(const int4*)(mbase + tp1 * KT + 24);

    // ---- QK: S^T[key][q], 4 MFMAs over d-slices. A = K frag from LDS:
    // row = 32kg+l31, chunk = 2s+h (d = 16s+8h+j), swizzled by row&7 == x7.
    f32x16 sacc = {0.f,0.f,0.f,0.f,0.f,0.f,0.f,0.f,0.f,0.f,0.f,0.f,0.f,0.f,0.f,0.f};
    {
      const uint8_t* krow = kbc + (32 * kg + l31) * 128;
      bf16x8 kf0 = *(const bf16x8*)(krow + (((0 + h) ^ x7) << 4));
      bf16x8 kf1 = *(const bf16x8*)(krow + (((2 + h) ^ x7) << 4));
      bf16x8 kf2 = *(const bf16x8*)(krow + (((4 + h) ^ x7) << 4));
      bf16x8 kf3 = *(const bf16x8*)(krow + (((6 + h) ^ x7) << 4));
      sacc = MFMA32(kf0, qf0, sacc);
      sacc = MFMA32(kf1, qf1, sacc);
      sacc = MFMA32(kf2, qf2, sacc);
      sacc = MFMA32(kf3, qf3, sacc);
    }

    // ---- softmax: p = exp2(s) (SCL2 pre-folded into Q), masked -> 0.
    // reg x holds local key (x&3)+8*(x>>2)+4h; mask int4 m=(x>>2), comp (x&3).
    float p0  = (mi0.x != 0) ? __builtin_amdgcn_exp2f(sacc[0])  : 0.f;
    float p1  = (mi0.y != 0) ? __builtin_amdgcn_exp2f(sacc[1])  : 0.f;
    float p2  = (mi0.z != 0) ? __builtin_amdgcn_exp2f(sacc[2])  : 0.f;
    float p3  = (mi0.w != 0) ? __builtin_amdgcn_exp2f(sacc[3])  : 0.f;
    float p4  = (mi1.x != 0) ? __builtin_amdgcn_exp2f(sacc[4])  : 0.f;
    float p5  = (mi1.y != 0) ? __builtin_amdgcn_exp2f(sacc[5])  : 0.f;
    float p6  = (mi1.z != 0) ? __builtin_amdgcn_exp2f(sacc[6])  : 0.f;
    float p7  = (mi1.w != 0) ? __builtin_amdgcn_exp2f(sacc[7])  : 0.f;
    float p8  = (mi2.x != 0) ? __builtin_amdgcn_exp2f(sacc[8])  : 0.f;
    float p9  = (mi2.y != 0) ? __builtin_amdgcn_exp2f(sacc[9])  : 0.f;
    float p10 = (mi2.z != 0) ? __builtin_amdgcn_exp2f(sacc[10]) : 0.f;
    float p11 = (mi2.w != 0) ? __builtin_amdgcn_exp2f(sacc[11]) : 0.f;
    float p12 = (mi3.x != 0) ? __builtin_amdgcn_exp2f(sacc[12]) : 0.f;
    float p13 = (mi3.y != 0) ? __builtin_amdgcn_exp2f(sacc[13]) : 0.f;
    float p14 = (mi3.z != 0) ? __builtin_amdgcn_exp2f(sacc[14]) : 0.f;
    float p15 = (mi3.w != 0) ? __builtin_amdgcn_exp2f(sacc[15]) : 0.f;
    lrun += ((p0 + p1) + (p2 + p3)) + ((p4 + p5) + (p6 + p7)) +
            ((p8 + p9) + (p10 + p11)) + ((p12 + p13) + (p14 + p15));

    // ---- P -> PV B-operand, fully in-register.
    // pk[i] = bf16pair(p[2i], p[2i+1]) covers keys 8*(i>>1)+2*(i&1)+4h (+1).
    // B-frag[ks] word w holds keys 16ks+8h+2w,+1. w<2 sources the LOWER
    // half-wave's pk, w>=2 the UPPER's; LSWAP routes both halves correctly.
    unsigned k0 = pk2(p0, p1),   k1 = pk2(p2, p3),
             k2 = pk2(p4, p5),   k3 = pk2(p6, p7),
             k4 = pk2(p8, p9),   k5 = pk2(p10, p11),
             k6 = pk2(p12, p13), k7 = pk2(p14, p15);
    uint4 bw;
    LSWAP(k0, k2);  // k0 -> word0 (ks=0), k2 -> word2
    LSWAP(k1, k3);  // k1 -> word1, k3 -> word3
    bw.x = k0; bw.y = k1; bw.z = k2; bw.w = k3;
    bf16x8 pB0 = __builtin_bit_cast(bf16x8, bw);
    LSWAP(k4, k6);
    LSWAP(k5, k7);
    bw.x = k4; bw.y = k5; bw.z = k6; bw.w = k7;
    bf16x8 pB1 = __builtin_bit_cast(bf16x8, bw);

    // ---- PV: O^T[d][q] += V^T.P^T. A = V^T frag: row d = 32dg+l31,
    // logical chunk 4kg+2ks+h, physical = logical ^ gvx ^ 4dg.
    {
      const uint8_t* vrow0 = vbc + (l31) * 128;        // dg=0
      const uint8_t* vrow1 = vbc + (32 + l31) * 128;   // dg=1
      bf16x8 vf0 = *(const bf16x8*)(vrow0 + (((4 * kg + 0 + h) ^ gvx) << 4));
      bf16x8 vf1 = *(const bf16x8*)(vrow0 + (((4 * kg + 2 + h) ^ gvx) << 4));
      bf16x8 vf2 = *(const bf16x8*)(vrow1 + (((4 * kg + 0 + h) ^ gvx ^ 4) << 4));
      bf16x8 vf3 = *(const bf16x8*)(vrow1 + (((4 * kg + 2 + h) ^ gvx ^ 4) << 4));
      oacc0 = MFMA32(vf0, pB0, oacc0);
      oacc0 = MFMA32(vf1, pB1, oacc0);
      oacc1 = MFMA32(vf2, pB0, oacc1);
      oacc1 = MFMA32(vf3, pB1, oacc1);
    }

    mi0 = mn0; mi1 = mn1; mi2 = mn2; mi3 = mn3;

    // ---- single barrier: WAR on buf[cur] + visibility of buf[nxt] staging.
    BAR();
  }

  // ---- epilogue 1: combine lane-pair (l <-> l+32) denominators via shfl
  // (guaranteed semantics; LSWAP-with-identical-operands degenerates: r14).
  const float l32 = lrun + __shfl_xor(lrun, 32);

  // ---- epilogue 2: cross-wave (kg=0 <-> kg=1) reduction via dead K/V LDS.
  // Waves 0,2 share qg=0 rows; waves 1,3 share qg=1. kg=1 writes partials,
  // kg=0 combines + stores. Padded stride 68 floats (<=8-way, once/block).
  float* xs = (float*)smem;
  const int xbase = qg * 2176 + l31 * 68;  // [qg][q=l31][d], stride 68
  if (kg == 1) {
#pragma unroll
    for (int xq = 0; xq < 4; ++xq) {
      float4 o;
      o.x = oacc0[4*xq+0]; o.y = oacc0[4*xq+1]; o.z = oacc0[4*xq+2]; o.w = oacc0[4*xq+3];
      *(float4*)(xs + xbase + 8 * xq + 4 * h) = o;         // d = 8xq+4h..+3
      o.x = oacc1[4*xq+0]; o.y = oacc1[4*xq+1]; o.z = oacc1[4*xq+2]; o.w = oacc1[4*xq+3];
      *(float4*)(xs + xbase + 32 + 8 * xq + 4 * h) = o;    // d = 32+8xq+4h..+3
    }
    if (h == 0) xs[4352 + qg * 32 + l31] = l32;
  }
  BAR();
  if (kg == 0) {
    const float ltot = l32 + xs[4352 + qg * 32 + l31];
    const float inv = (ltot > 0.f) ? (1.f / ltot) : 0.f;
    float* orow = out + base + (size_t)qrow * DD;
#pragma unroll
    for (int xq = 0; xq < 4; ++xq) {
      float4 po = *(const float4*)(xs + xbase + 8 * xq + 4 * h);
      float4 o;
      o.x = (oacc0[4*xq+0] + po.x) * inv;
      o.y = (oacc0[4*xq+1] + po.y) * inv;
      o.z = (oacc0[4*xq+2] + po.z) * inv;
      o.w = (oacc0[4*xq+3] + po.w) * inv;
      *(float4*)(orow + 8 * xq + 4 * h) = o;
      po = *(const float4*)(xs + xbase + 32 + 8 * xq + 4 * h);
      o.x = (oacc1[4*xq+0] + po.x) * inv;
      o.y = (oacc1[4*xq+1] + po.y) * inv;
      o.z = (oacc1[4*xq+2] + po.z) * inv;
      o.w = (oacc1[4*xq+3] + po.w) * inv;
      *(float4*)(orow + 32 + 8 * xq + 4 * h) = o;
    }
  }
}

extern "C" void kernel_launch(void* const* d_in, const int* in_sizes, int n_in,
                              void* d_out, int out_size, void* d_ws, size_t ws_size,
                              hipStream_t stream) {
  (void)in_sizes; (void)n_in; (void)out_size; (void)d_ws; (void)ws_size;
  const float* Q = (const float*)d_in[0];
  const float* K = (const float*)d_in[1];
  const float* V = (const float*)d_in[2];
  const int* mask = (const int*)d_in[3];
  float* out = (float*)d_out;
  attn_mfma<<<1024, 256, 0, stream>>>(Q, K, V, mask, out);
}

// Round 10
// 210.044 us; speedup vs baseline: 1.1626x; 1.0009x over previous
//
#include <hip/hip_runtime.h>
#include <stdint.h>

// B=2, H=16, S=2048, D=64. fp32 in, fp32 out. mask int32 [B,1,S,S].
// scores = QK^T/8, masked_fill(mask==0, -32768), softmax, @V.
// Fixed-max softmax in exp2 domain: p = exp2(s*log2e/8); masked -> exact 0.
//
// ROUND 19 == r18 + cross-iteration PV pipeline (latency-chain attack).
// r18 evidence: conflicts fixed (1.9e7->4.3e6) yet dur identical to r15 ->
// conflicts were off the critical path. All pipes >=75% idle => per-tile
// serial chain (QK->softmax->PV) x 128 lockstep phases is the limiter.
// Change: PV(t-1) executes in iteration t, overlapping QK(t) (independent
// MFMA chains, 2x MFMA ILP per phase; PV no longer behind softmax).
//  - V triple-buffered (V(t-1) live while V(t+1) stages): LDS 40960.
//  - WAR: stage(t+1)->vbN != vbP (3-rotation); one end-of-tile barrier
//    separates stage(t+2) from QK(t)/PV(t-1) reads. K stays 2-buffered.
//  - Epilogue: PV(NT-1) after final barrier; xs region (0..17.7KB) disjoint
//    from V1 (24.5KB+) where final PV reads.
// Everything else byte-identical to r18 (verified mappings, two-level V
// swizzle, coalesced roles, SCL2-folded Q, lgkm-only barrier, prefetches).

#define SS 2048
#define DD 64
#define KT 64
#define NT 32
#define QB 64

#define KS0 0
#define KS1 8192
#define VT0 16384
#define VT1 24576
#define VT2 32768
#define SMEM_SZ 40960

#define SCL2 0.18033688011112042f  // log2(e)/8

typedef __attribute__((ext_vector_type(8))) short bf16x8;
typedef __attribute__((ext_vector_type(16))) float f32x16;

// pack two f32 -> two bf16 (RNE): low16 = bf16(f0), high16 = bf16(f1)
static __device__ __forceinline__ unsigned pk2(float f0, float f1) {
  unsigned r;
  asm("v_cvt_pk_bf16_f32 %0, %1, %2" : "=v"(r) : "v"(f0), "v"(f1));
  return r;
}

// v_permlane32_swap_b32 a, b:
//   a' = {a[0:31], b[0:31]}, b' = {a[32:63], b[32:63]}
#define LSWAP(A, B) asm("v_permlane32_swap_b32 %0, %1" : "+v"(A), "+v"(B))

// barrier with LDS visibility only: lgkmcnt(0) + s_barrier. vmcnt untouched so
// register prefetches issued this iteration stay in flight across it.
#define BAR() do {                              \
  asm volatile("" ::: "memory");                \
  __builtin_amdgcn_s_waitcnt(0xC07F);           \
  __builtin_amdgcn_s_barrier();                 \
  asm volatile("" ::: "memory");                \
} while (0)

#define MFMA32(A, B, C) __builtin_amdgcn_mfma_f32_32x32x16_bf16((A), (B), (C), 0, 0, 0)

__global__ __launch_bounds__(256, 2)
void attn_mfma(const float* __restrict__ Q, const float* __restrict__ K,
               const float* __restrict__ V, const int* __restrict__ mask,
               float* __restrict__ out) {
  __shared__ alignas(16) uint8_t smem[SMEM_SZ];

  const int tid = threadIdx.x;
  const int wv = tid >> 6;
  const int l = tid & 63;
  const int l31 = l & 31;   // MFMA n-dim (q) / m-dim (key,d) lane index
  const int h = l >> 5;     // lane half: k-dim slice 8h+j
  const int x7 = l & 7;     // row&7 for K rows base+l31

  const int qg = wv & 1;    // q-group within block (32 q each)
  const int kg = wv >> 1;   // key-group within tile (32 keys each)

  const int bid = blockIdx.x;  // 1024 = 32 (b,h) x 32 q-blocks
  const int qblk = bid & 31;
  const int bh = bid >> 5;
  const int b = bh >> 4;
  const size_t base = (size_t)bh * SS * DD;
  const int qrow = qblk * QB + 32 * qg + l31;  // this lane's query row

  // K staging: row kr (key), 16-col chunk kq. 2x b128 per thread.
  const int kr = tid >> 2;
  const int kq = tid & 3;
  // V staging roles (coalesced): key-quad va_ = tid>>4, d-quad vc = tid&15.
  const int va_ = tid >> 4;
  const int vc = tid & 15;
  // V^T write swizzle: row_i = 4vc+i -> row&7 = 4(vc&1)+i, row>>3 = vc>>1.
  const int vc1 = 4 * (vc & 1);
  const int vch = vc >> 1;
  const int vsub = 8 * (va_ & 1);
  const int vcq = va_ >> 1;
  // V^T read swizzle: g(row=32dg+l31) = x7 ^ (l31>>3) ^ 4dg
  const int gvx = x7 ^ (l31 >> 3);

  // ---- Q fragments (one-time), PRE-SCALED by SCL2:
  bf16x8 qf0, qf1, qf2, qf3;
  {
    const float* qp = Q + base + (size_t)qrow * DD + 8 * h;
    uint4 pk;
    float4 qa, qb;
    qa = *(const float4*)(qp);      qb = *(const float4*)(qp + 4);
    pk.x = pk2(qa.x * SCL2, qa.y * SCL2); pk.y = pk2(qa.z * SCL2, qa.w * SCL2);
    pk.z = pk2(qb.x * SCL2, qb.y * SCL2); pk.w = pk2(qb.z * SCL2, qb.w * SCL2);
    qf0 = __builtin_bit_cast(bf16x8, pk);
    qa = *(const float4*)(qp + 16); qb = *(const float4*)(qp + 20);
    pk.x = pk2(qa.x * SCL2, qa.y * SCL2); pk.y = pk2(qa.z * SCL2, qa.w * SCL2);
    pk.z = pk2(qb.x * SCL2, qb.y * SCL2); pk.w = pk2(qb.z * SCL2, qb.w * SCL2);
    qf1 = __builtin_bit_cast(bf16x8, pk);
    qa = *(const float4*)(qp + 32); qb = *(const float4*)(qp + 36);
    pk.x = pk2(qa.x * SCL2, qa.y * SCL2); pk.y = pk2(qa.z * SCL2, qa.w * SCL2);
    pk.z = pk2(qb.x * SCL2, qb.y * SCL2); pk.w = pk2(qb.z * SCL2, qb.w * SCL2);
    qf2 = __builtin_bit_cast(bf16x8, pk);
    qa = *(const float4*)(qp + 48); qb = *(const float4*)(qp + 52);
    pk.x = pk2(qa.x * SCL2, qa.y * SCL2); pk.y = pk2(qa.z * SCL2, qa.w * SCL2);
    pk.z = pk2(qb.x * SCL2, qb.y * SCL2); pk.w = pk2(qb.z * SCL2, qb.w * SCL2);
    qf3 = __builtin_bit_cast(bf16x8, pk);
  }

  // O^T accumulators: oacc[dg] reg x -> O[q=qrow][d = 32dg + (x&3)+8(x>>2)+4h]
  f32x16 oacc0 = {0.f,0.f,0.f,0.f,0.f,0.f,0.f,0.f,0.f,0.f,0.f,0.f,0.f,0.f,0.f,0.f};
  f32x16 oacc1 = {0.f,0.f,0.f,0.f,0.f,0.f,0.f,0.f,0.f,0.f,0.f,0.f,0.f,0.f,0.f,0.f};
  float lrun = 0.f;  // own-16-keys partial

  float4 kL0, kL1, kL2, kL3, vL0, vL1, vL2, vL3;

#define LOADKV(T) do {                                                    \
    const float* kp_ = K + base + (size_t)((T)*KT + kr) * DD + kq * 16;   \
    kL0 = *(const float4*)(kp_);                                          \
    kL1 = *(const float4*)(kp_ + 4);                                      \
    kL2 = *(const float4*)(kp_ + 8);                                      \
    kL3 = *(const float4*)(kp_ + 12);                                     \
    const float* vp_ = V + base + (size_t)((T)*KT + 4 * va_) * DD + 4 * vc;\
    vL0 = *(const float4*)(vp_);                                          \
    vL1 = *(const float4*)(vp_ + DD);                                     \
    vL2 = *(const float4*)(vp_ + 2 * DD);                                 \
    vL3 = *(const float4*)(vp_ + 3 * DD);                                 \
  } while (0)

  // K rows: 64 x 128B, logical chunk c stored at ((c ^ (row&7))<<4).
  // V^T rows: 64 x 128B (row=d), chunk c=key>>3 stored at
  // ((c ^ (row&7) ^ ((row>>3)&7))<<4); 8B sub-slot 8*(va_&1).
#define STAGE(KB, VB) do {                                                \
    uint4 c_;                                                             \
    c_.x = pk2(kL0.x, kL0.y); c_.y = pk2(kL0.z, kL0.w);                   \
    c_.z = pk2(kL1.x, kL1.y); c_.w = pk2(kL1.z, kL1.w);                   \
    *(uint4*)((KB) + kr * 128 + (((2 * kq) ^ (kr & 7)) << 4)) = c_;       \
    c_.x = pk2(kL2.x, kL2.y); c_.y = pk2(kL2.z, kL2.w);                   \
    c_.z = pk2(kL3.x, kL3.y); c_.w = pk2(kL3.z, kL3.w);                   \
    *(uint4*)((KB) + kr * 128 + (((2 * kq + 1) ^ (kr & 7)) << 4)) = c_;   \
    uint2 w_;                                                             \
    w_.x = pk2(vL0.x, vL1.x); w_.y = pk2(vL2.x, vL3.x);                   \
    *(uint2*)((VB) + (4*vc+0) * 128 + (((vcq ^ (vc1 + 0) ^ vch) << 4)) + vsub) = w_; \
    w_.x = pk2(vL0.y, vL1.y); w_.y = pk2(vL2.y, vL3.y);                   \
    *(uint2*)((VB) + (4*vc+1) * 128 + (((vcq ^ (vc1 + 1) ^ vch) << 4)) + vsub) = w_; \
    w_.x = pk2(vL0.z, vL1.z); w_.y = pk2(vL2.z, vL3.z);                   \
    *(uint2*)((VB) + (4*vc+2) * 128 + (((vcq ^ (vc1 + 2) ^ vch) << 4)) + vsub) = w_; \
    w_.x = pk2(vL0.w, vL1.w); w_.y = pk2(vL2.w, vL3.w);                   \
    *(uint2*)((VB) + (4*vc+3) * 128 + (((vcq ^ (vc1 + 3) ^ vch) << 4)) + vsub) = w_; \
  } while (0)

  // ---- prologue: tile 0 staged to K0/V0; tile 1 in regs; mask tile 0 in regs
  LOADKV(0);
  STAGE(smem + KS0, smem + VT0);
  LOADKV(1);

  // mask: lane needs keys 32kg + 4h + {0..3, 8..11, 16..19, 24..27} of its qrow
  const int* mbase = mask + (size_t)b * SS * SS + (size_t)qrow * SS + 32 * kg + 4 * h;
  int4 mi0 = *(const int4*)(mbase + 0);
  int4 mi1 = *(const int4*)(mbase + 8);
  int4 mi2 = *(const int4*)(mbase + 16);
  int4 mi3 = *(const int4*)(mbase + 24);

  // buffer rotation state
  uint8_t* kbC = smem + KS0;  // K(t)
  uint8_t* kbN = smem + KS1;  // stage target K(t+1)
  uint8_t* vbP = smem + VT2;  // V(t-1)  (empty at t=0; PV skipped)
  uint8_t* vbC = smem + VT0;  // V(t)
  uint8_t* vbN = smem + VT1;  // stage target V(t+1)

  bf16x8 pB0p = {0,0,0,0,0,0,0,0}, pB1p = {0,0,0,0,0,0,0,0};  // P(t-1)

  BAR();

  for (int t = 0; t < NT; ++t) {
    // ---- PV(t-1): O^T += V^T(t-1).P^T(t-1). Independent of QK(t) ->
    // two MFMA chains overlap in this phase. Skipped at t=0.
    if (t > 0) {
      const uint8_t* vrow0 = vbP + (l31) * 128;        // dg=0
      const uint8_t* vrow1 = vbP + (32 + l31) * 128;   // dg=1
      bf16x8 vf0 = *(const bf16x8*)(vrow0 + (((4 * kg + 0 + h) ^ gvx) << 4));
      bf16x8 vf1 = *(const bf16x8*)(vrow0 + (((4 * kg + 2 + h) ^ gvx) << 4));
      bf16x8 vf2 = *(const bf16x8*)(vrow1 + (((4 * kg + 0 + h) ^ gvx ^ 4) << 4));
      bf16x8 vf3 = *(const bf16x8*)(vrow1 + (((4 * kg + 2 + h) ^ gvx ^ 4) << 4));
      oacc0 = MFMA32(vf0, pB0p, oacc0);
      oacc0 = MFMA32(vf1, pB1p, oacc0);
      oacc1 = MFMA32(vf2, pB0p, oacc1);
      oacc1 = MFMA32(vf3, pB1p, oacc1);
    }

    // ---- QK(t): S^T[key][q], 4 MFMAs over d-slices, from kbC.
    f32x16 sacc = {0.f,0.f,0.f,0.f,0.f,0.f,0.f,0.f,0.f,0.f,0.f,0.f,0.f,0.f,0.f,0.f};
    {
      const uint8_t* krow = kbC + (32 * kg + l31) * 128;
      bf16x8 kf0 = *(const bf16x8*)(krow + (((0 + h) ^ x7) << 4));
      bf16x8 kf1 = *(const bf16x8*)(krow + (((2 + h) ^ x7) << 4));
      bf16x8 kf2 = *(const bf16x8*)(krow + (((4 + h) ^ x7) << 4));
      bf16x8 kf3 = *(const bf16x8*)(krow + (((6 + h) ^ x7) << 4));
      sacc = MFMA32(kf0, qf0, sacc);
      sacc = MFMA32(kf1, qf1, sacc);
      sacc = MFMA32(kf2, qf2, sacc);
      sacc = MFMA32(kf3, qf3, sacc);
    }

    // ---- stage tile t+1 (regs) into kbN/vbN (disjoint from kbC and vbP).
    if (t + 1 < NT) STAGE(kbN, vbN);

    // ---- prefetch tile t+2 K/V into regs (spans barrier; vmcnt never drained)
    const int tp2 = (t + 2 < NT) ? (t + 2) : (NT - 1);
    LOADKV(tp2);
    // ---- prefetch mask tile t+1
    const int tp1 = (t + 1 < NT) ? (t + 1) : (NT - 1);
    int4 mn0 = *(const int4*)(mbase + tp1 * KT + 0);
    int4 mn1 = *(const int4*)(mbase + tp1 * KT + 8);
    int4 mn2 = *(const int4*)(mbase + tp1 * KT + 16);
    int4 mn3 = *(const int4*)(mbase + tp1 * KT + 24);

    // ---- softmax(t): p = exp2(s) (SCL2 pre-folded), masked -> 0.
    float p0  = (mi0.x != 0) ? __builtin_amdgcn_exp2f(sacc[0])  : 0.f;
    float p1  = (mi0.y != 0) ? __builtin_amdgcn_exp2f(sacc[1])  : 0.f;
    float p2  = (mi0.z != 0) ? __builtin_amdgcn_exp2f(sacc[2])  : 0.f;
    float p3  = (mi0.w != 0) ? __builtin_amdgcn_exp2f(sacc[3])  : 0.f;
    float p4  = (mi1.x != 0) ? __builtin_amdgcn_exp2f(sacc[4])  : 0.f;
    float p5  = (mi1.y != 0) ? __builtin_amdgcn_exp2f(sacc[5])  : 0.f;
    float p6  = (mi1.z != 0) ? __builtin_amdgcn_exp2f(sacc[6])  : 0.f;
    float p7  = (mi1.w != 0) ? __builtin_amdgcn_exp2f(sacc[7])  : 0.f;
    float p8  = (mi2.x != 0) ? __builtin_amdgcn_exp2f(sacc[8])  : 0.f;
    float p9  = (mi2.y != 0) ? __builtin_amdgcn_exp2f(sacc[9])  : 0.f;
    float p10 = (mi2.z != 0) ? __builtin_amdgcn_exp2f(sacc[10]) : 0.f;
    float p11 = (mi2.w != 0) ? __builtin_amdgcn_exp2f(sacc[11]) : 0.f;
    float p12 = (mi3.x != 0) ? __builtin_amdgcn_exp2f(sacc[12]) : 0.f;
    float p13 = (mi3.y != 0) ? __builtin_amdgcn_exp2f(sacc[13]) : 0.f;
    float p14 = (mi3.z != 0) ? __builtin_amdgcn_exp2f(sacc[14]) : 0.f;
    float p15 = (mi3.w != 0) ? __builtin_amdgcn_exp2f(sacc[15]) : 0.f;
    lrun += ((p0 + p1) + (p2 + p3)) + ((p4 + p5) + (p6 + p7)) +
            ((p8 + p9) + (p10 + p11)) + ((p12 + p13) + (p14 + p15));

    // ---- P(t) -> B-operand regs for next iteration's PV.
    unsigned k0 = pk2(p0, p1),   k1 = pk2(p2, p3),
             k2 = pk2(p4, p5),   k3 = pk2(p6, p7),
             k4 = pk2(p8, p9),   k5 = pk2(p10, p11),
             k6 = pk2(p12, p13), k7 = pk2(p14, p15);
    uint4 bw;
    LSWAP(k0, k2);
    LSWAP(k1, k3);
    bw.x = k0; bw.y = k1; bw.z = k2; bw.w = k3;
    pB0p = __builtin_bit_cast(bf16x8, bw);
    LSWAP(k4, k6);
    LSWAP(k5, k7);
    bw.x = k4; bw.y = k5; bw.z = k6; bw.w = k7;
    pB1p = __builtin_bit_cast(bf16x8, bw);

    mi0 = mn0; mi1 = mn1; mi2 = mn2; mi3 = mn3;

    // ---- rotate buffers; single barrier: WAR on kbC/vbP + visibility of
    // kbN/vbN staging. lgkm-only (prefetch loads stay in flight).
    uint8_t* kt_ = kbC; kbC = kbN; kbN = kt_;
    uint8_t* vt_ = vbP; vbP = vbC; vbC = vbN; vbN = vt_;
    BAR();
  }

  // ---- epilogue 0: final PV(NT-1). vbP = V(NT-1) after last rotation;
  // reads VT1 (24.5K+), disjoint from xs region below (0..17.7K).
  {
    const uint8_t* vrow0 = vbP + (l31) * 128;
    const uint8_t* vrow1 = vbP + (32 + l31) * 128;
    bf16x8 vf0 = *(const bf16x8*)(vrow0 + (((4 * kg + 0 + h) ^ gvx) << 4));
    bf16x8 vf1 = *(const bf16x8*)(vrow0 + (((4 * kg + 2 + h) ^ gvx) << 4));
    bf16x8 vf2 = *(const bf16x8*)(vrow1 + (((4 * kg + 0 + h) ^ gvx ^ 4) << 4));
    bf16x8 vf3 = *(const bf16x8*)(vrow1 + (((4 * kg + 2 + h) ^ gvx ^ 4) << 4));
    oacc0 = MFMA32(vf0, pB0p, oacc0);
    oacc0 = MFMA32(vf1, pB1p, oacc0);
    oacc1 = MFMA32(vf2, pB0p, oacc1);
    oacc1 = MFMA32(vf3, pB1p, oacc1);
  }

  // ---- epilogue 1: combine lane-pair (l <-> l+32) denominators via shfl.
  const float l32 = lrun + __shfl_xor(lrun, 32);

  // ---- epilogue 2: cross-wave (kg=0 <-> kg=1) reduction via dead K LDS.
  float* xs = (float*)smem;
  const int xbase = qg * 2176 + l31 * 68;  // [qg][q=l31][d], stride 68
  if (kg == 1) {
#pragma unroll
    for (int xq = 0; xq < 4; ++xq) {
      float4 o;
      o.x = oacc0[4*xq+0]; o.y = oacc0[4*xq+1]; o.z = oacc0[4*xq+2]; o.w = oacc0[4*xq+3];
      *(float4*)(xs + xbase + 8 * xq + 4 * h) = o;         // d = 8xq+4h..+3
      o.x = oacc1[4*xq+0]; o.y = oacc1[4*xq+1]; o.z = oacc1[4*xq+2]; o.w = oacc1[4*xq+3];
      *(float4*)(xs + xbase + 32 + 8 * xq + 4 * h) = o;    // d = 32+8xq+4h..+3
    }
    if (h == 0) xs[4352 + qg * 32 + l31] = l32;
  }
  BAR();
  if (kg == 0) {
    const float ltot = l32 + xs[4352 + qg * 32 + l31];
    const float inv = (ltot > 0.f) ? (1.f / ltot) : 0.f;
    float* orow = out + base + (size_t)qrow * DD;
#pragma unroll
    for (int xq = 0; xq < 4; ++xq) {
      float4 po = *(const float4*)(xs + xbase + 8 * xq + 4 * h);
      float4 o;
      o.x = (oacc0[4*xq+0] + po.x) * inv;
      o.y = (oacc0[4*xq+1] + po.y) * inv;
      o.z = (oacc0[4*xq+2] + po.z) * inv;
      o.w = (oacc0[4*xq+3] + po.w) * inv;
      *(float4*)(orow + 8 * xq + 4 * h) = o;
      po = *(const float4*)(xs + xbase + 32 + 8 * xq + 4 * h);
      o.x = (oacc1[4*xq+0] + po.x) * inv;
      o.y = (oacc1[4*xq+1] + po.y) * inv;
      o.z = (oacc1[4*xq+2] + po.z) * inv;
      o.w = (oacc1[4*xq+3] + po.w) * inv;
      *(float4*)(orow + 32 + 8 * xq + 4 * h) = o;
    }
  }
}

extern "C" void kernel_launch(void* const* d_in, const int* in_sizes, int n_in,
                              void* d_out, int out_size, void* d_ws, size_t ws_size,
                              hipStream_t stream) {
  (void)in_sizes; (void)n_in; (void)out_size; (void)d_ws; (void)ws_size;
  const float* Q = (const float*)d_in[0];
  const float* K = (const float*)d_in[1];
  const float* V = (const float*)d_in[2];
  const int* mask = (const int*)d_in[3];
  float* out = (float*)d_out;
  attn_mfma<<<1024, 256, 0, stream>>>(Q, K, V, mask, out);
}